// Round 9
// baseline (202.072 us; speedup 1.0000x reference)
//
#include <hip/hip_runtime.h>

#define IMG_H 512
#define IMG_W 512
#define BATCH 32
#define TH 32               // output rows per wave-strip
#define NR (TH + 6)         // 38 input rows
#define OUTW 58             // output cols per wave (lanes 3..60)
#define NTILE 9             // ceil(512/58)
#define NUNIT (NTILE * 16 * BATCH)  // 4608 wave-units

__device__ __forceinline__ float bperm(int addr, float v) {
  return __int_as_float(__builtin_amdgcn_ds_bpermute(addr, __float_as_int(v)));
}

// Wave-autonomous SSIM: each wave owns a 64-col x (TH+6)-row strip.
// 2 coalesced loads per input row; horizontal halo via ds_bpermute
// (deterministic register exchange -- no LDS staging, no barriers anywhere).
// Depth-4 register prefetch ring; per-row waits are fine-grained vmcnt.
__global__ __launch_bounds__(128) void ssim_main(
    const float* __restrict__ X, const float* __restrict__ Y,
    const float* __restrict__ K, float* __restrict__ partials) {
  const int t = threadIdx.x;
  const int wv = t >> 6;              // wave in block (0..1), independent
  const int ln = t & 63;
  const int tile = blockIdx.x;        // 0..8
  const int strip = blockIdx.y * 2 + wv;  // 0..15
  const int y0 = strip * TH;
  const size_t img = (size_t)IMG_H * IMG_W;
  const float* Xb = X + blockIdx.z * img;
  const float* Yb = Y + blockIdx.z * img;

  // Exact separable 1D weights from center row of the provided 7x7 kernel:
  // k[3][j] = w3*w_j, sum_j w_j = 1  =>  w_j = k[3][j] / sum_j k[3][j].
  float w[7];
  {
    float rs = 0.f;
#pragma unroll
    for (int j = 0; j < 7; ++j) { w[j] = K[3 * 7 + j]; rs += w[j]; }
    const float inv = 1.f / rs;
#pragma unroll
    for (int j = 0; j < 7; ++j) w[j] *= inv;
  }

  // This lane's column; clamped load col; masked h-weights (exact zero-pad).
  const int c = tile * OUTW - 3 + ln;
  const int cc = min(max(c, 0), IMG_W - 1);
  float wk[7];
#pragma unroll
  for (int j = 0; j < 7; ++j)
    wk[j] = ((unsigned)(c - 3 + j) < (unsigned)IMG_W) ? w[j] : 0.f;
  const bool valid = (ln >= 3) && (ln <= 60) && (c < IMG_W);
  const float vmask = valid ? 1.f : 0.f;

  // bpermute byte-addresses for tap offsets -3..+3 (skip 0); wrap is safe:
  // wrapped lanes hold finite image data and those outputs are vmask'ed.
  int sa[7];
#pragma unroll
  for (int j = 0; j < 7; ++j) sa[j] = (((ln + j - 3) & 63) << 2);

  // mod-7 ring of 5-channel vertical accumulators (all indices fold).
  float acc[7][5];
#pragma unroll
  for (int s = 0; s < 7; ++s)
#pragma unroll
    for (int ch = 0; ch < 5; ++ch) acc[s][ch] = 0.f;
  float tsum = 0.f;

  // Depth-4 register prefetch ring (2 loads per row, coalesced).
  float xr[4], yr[4];
  auto load_row = [&](int r) {
    const int gy = y0 - 3 + r;
    const int gyc = min(max(gy, 0), IMG_H - 1);
    const size_t off = (size_t)gyc * IMG_W + cc;
    xr[r & 3] = Xb[off];
    yr[r & 3] = Yb[off];
  };

  load_row(0); load_row(1); load_row(2); load_row(3);

#pragma unroll
  for (int r = 0; r < NR; ++r) {      // fully unrolled, r compile-time
    const int b = r & 3;

    // 7-tap windows via cross-lane bpermute (own value for tap 3)
    float xw[7], yw[7];
#pragma unroll
    for (int j = 0; j < 7; ++j) {
      if (j == 3) { xw[j] = xr[b]; yw[j] = yr[b]; }
      else        { xw[j] = bperm(sa[j], xr[b]); yw[j] = bperm(sa[j], yr[b]); }
    }

    if (r + 4 < NR) load_row(r + 4);  // reuse ring slot b, issued early

    // horizontal 7-tap, 5 channels (masked weights = exact x zero-pad)
    float hx = 0.f, hy = 0.f, hxx = 0.f, hyy = 0.f, hxy = 0.f;
#pragma unroll
    for (int j = 0; j < 7; ++j) {
      const float wx = wk[j] * xw[j];
      const float wy = wk[j] * yw[j];
      hx  = fmaf(wk[j], xw[j], hx);
      hy  = fmaf(wk[j], yw[j], hy);
      hxx = fmaf(wx, xw[j], hxx);
      hyy = fmaf(wy, yw[j], hyy);
      hxy = fmaf(wx, yw[j], hxy);
    }

    // y-edge SAME padding: zero OOB rows' contribution (wave-uniform mask)
    const int gy = y0 - 3 + r;
    const float rm = ((unsigned)gy < (unsigned)IMG_H) ? 1.f : 0.f;
    hx *= rm; hy *= rm; hxx *= rm; hyy *= rm; hxy *= rm;

    // vertical scatter into the ring; guards fold at compile time
#pragma unroll
    for (int tt = 0; tt < 7; ++tt) {
      const int o = r - tt;
      if (o >= 0 && o < TH) {
        const int slot = o % 7;
        const float wt = w[tt];
        acc[slot][0] = fmaf(wt, hx,  acc[slot][0]);
        acc[slot][1] = fmaf(wt, hy,  acc[slot][1]);
        acc[slot][2] = fmaf(wt, hxx, acc[slot][2]);
        acc[slot][3] = fmaf(wt, hyy, acc[slot][3]);
        acc[slot][4] = fmaf(wt, hxy, acc[slot][4]);
      }
    }

    // output row r-6 complete
    if (r >= 6) {
      const int slot = (r - 6) % 7;
      const float mu_x = acc[slot][0];
      const float mu_y = acc[slot][1];
      const float mx2 = mu_x * mu_x;
      const float my2 = mu_y * mu_y;
      const float mxy = mu_x * mu_y;
      const float sxx = acc[slot][2] - mx2;
      const float syy = acc[slot][3] - my2;
      const float sxy = acc[slot][4] - mxy;
      const float num = (2.f * mxy + 1e-4f) * (2.f * sxy + 9e-4f);
      const float den = (mx2 + my2 + 1e-4f) * (sxx + syy + 9e-4f);
      tsum += vmask * (num * __builtin_amdgcn_rcpf(den));
#pragma unroll
      for (int ch = 0; ch < 5; ++ch) acc[slot][ch] = 0.f;
    }
  }

  // wave64 reduction -> one plain store per wave-unit; no barriers at all.
#pragma unroll
  for (int off = 32; off > 0; off >>= 1) tsum += __shfl_down(tsum, off);
  if (ln == 0) {
    const int uid = tile + NTILE * (strip + 16 * blockIdx.z);
    partials[uid] = tsum;
  }
}

__global__ __launch_bounds__(256) void ssim_reduce(
    const float* __restrict__ partials, float* __restrict__ out) {
  __shared__ double wsum[4];
  const int t = threadIdx.x;
  double s = 0.0;
#pragma unroll
  for (int i = 0; i < NUNIT / 256; ++i) s += (double)partials[t + 256 * i];
#pragma unroll
  for (int off = 32; off > 0; off >>= 1) s += __shfl_down(s, off);
  if ((t & 63) == 0) wsum[t >> 6] = s;
  __syncthreads();
  if (t == 0)
    out[0] = (float)((wsum[0] + wsum[1] + wsum[2] + wsum[3]) *
                     (1.0 / (double)((size_t)BATCH * IMG_H * IMG_W)));
}

extern "C" void kernel_launch(void* const* d_in, const int* in_sizes, int n_in,
                              void* d_out, int out_size, void* d_ws, size_t ws_size,
                              hipStream_t stream) {
  const float* X = (const float*)d_in[0];
  const float* Y = (const float*)d_in[1];
  const float* K = (const float*)d_in[2];
  float* out = (float*)d_out;
  float* partials = (float*)d_ws;   // NUNIT floats, all rewritten every launch

  dim3 grid(NTILE, 8, BATCH);       // 9 x 8 x 32 blocks of 128 (2 waves)
  hipLaunchKernelGGL(ssim_main, grid, dim3(128), 0, stream, X, Y, K, partials);
  hipLaunchKernelGGL(ssim_reduce, dim3(1), dim3(256), 0, stream, partials, out);
}